// Round 1
// baseline (273.284 us; speedup 1.0000x reference)
//
#include <hip/hip_runtime.h>
#include <hip/hip_bf16.h>

#define N_NODES 200000
#define N_EDGES 400000
#define F_IN    165
#define HID     128
#define SCAN_CHUNK 2048
#define SCAN_BLOCKS 98   // ceil(200000/2048)

// ---- CSR build ----------------------------------------------------------

__global__ __launch_bounds__(256) void k_count(const int* __restrict__ ei,
                                               int* __restrict__ counts) {
  int e = blockIdx.x * 256 + threadIdx.x;
  if (e < N_EDGES) atomicAdd(&counts[ei[N_EDGES + e]], 1);
}

__global__ __launch_bounds__(256) void k_dinv(const int* __restrict__ counts,
                                              float* __restrict__ dinv) {
  int i = blockIdx.x * 256 + threadIdx.x;
  if (i < N_NODES) dinv[i] = rsqrtf(1.0f + (float)counts[i]);
}

__global__ __launch_bounds__(256) void k_scan1(const int* __restrict__ counts,
                                               int* __restrict__ row_start,
                                               int* __restrict__ aux) {
  __shared__ int lds[256];
  int t = threadIdx.x;
  int base = blockIdx.x * SCAN_CHUNK + t * 8;
  int v[8], pre[8];
  int s = 0;
  #pragma unroll
  for (int j = 0; j < 8; ++j) {
    int i = base + j;
    v[j] = (i < N_NODES) ? counts[i] : 0;
    pre[j] = s;
    s += v[j];
  }
  lds[t] = s;
  __syncthreads();
  int incl = s;
  for (int off = 1; off < 256; off <<= 1) {
    int y = (t >= off) ? lds[t - off] : 0;
    __syncthreads();
    incl += y;
    lds[t] = incl;
    __syncthreads();
  }
  int excl = incl - s;
  #pragma unroll
  for (int j = 0; j < 8; ++j) {
    int i = base + j;
    if (i < N_NODES) row_start[i] = excl + pre[j];
  }
  if (t == 255) aux[blockIdx.x] = incl;
}

__global__ void k_scan2(int* __restrict__ aux) {  // 1 block, 128 threads
  __shared__ int lds[128];
  int t = threadIdx.x;
  int s = (t < SCAN_BLOCKS) ? aux[t] : 0;
  lds[t] = s;
  __syncthreads();
  int incl = s;
  for (int off = 1; off < 128; off <<= 1) {
    int y = (t >= off) ? lds[t - off] : 0;
    __syncthreads();
    incl += y;
    lds[t] = incl;
    __syncthreads();
  }
  if (t < SCAN_BLOCKS) aux[t] = incl - s;  // exclusive
}

__global__ __launch_bounds__(256) void k_scan3(int* __restrict__ row_start,
                                               const int* __restrict__ aux,
                                               int* __restrict__ cursor) {
  int i = blockIdx.x * 256 + threadIdx.x;
  if (i < N_NODES) {
    int r = row_start[i] + aux[i >> 11];
    row_start[i] = r;
    cursor[i] = r;
  }
}

__global__ __launch_bounds__(256) void k_place(const int* __restrict__ ei,
                                               int* __restrict__ cursor,
                                               int* __restrict__ csr) {
  int e = blockIdx.x * 256 + threadIdx.x;
  if (e < N_EDGES) {
    int d = ei[N_EDGES + e];
    int pos = atomicAdd(&cursor[d], 1);
    csr[pos] = ei[e];
  }
}

// ---- GEMM1: g = (x @ W1) * dinv[row]  ----------------------------------
// 64-row x tile in LDS, per-thread 8 rows x 4 cols register tile.

__global__ __launch_bounds__(256) void k_gemm1(const float* __restrict__ x,
                                               const float* __restrict__ W1,
                                               const float* __restrict__ dinv,
                                               float* __restrict__ g) {
  __shared__ float xs[64 * F_IN];
  const float* xg = x + (size_t)blockIdx.x * (64 * F_IN);
  for (int i = threadIdx.x; i < 64 * F_IN; i += 256) xs[i] = xg[i];
  __syncthreads();

  int cg = threadIdx.x & 31;   // col group: 4 cols each -> 128 cols
  int rg = threadIdx.x >> 5;   // row group: 8 rows each -> 64 rows
  float acc[8][4];
  #pragma unroll
  for (int r = 0; r < 8; ++r) {
    acc[r][0] = 0.f; acc[r][1] = 0.f; acc[r][2] = 0.f; acc[r][3] = 0.f;
  }
  const float* wp = W1 + cg * 4;
  #pragma unroll 5
  for (int k = 0; k < F_IN; ++k) {
    float4 w = *(const float4*)(wp + (size_t)k * HID);
    #pragma unroll
    for (int r = 0; r < 8; ++r) {
      float xv = xs[(rg * 8 + r) * F_IN + k];
      acc[r][0] = fmaf(xv, w.x, acc[r][0]);
      acc[r][1] = fmaf(xv, w.y, acc[r][1]);
      acc[r][2] = fmaf(xv, w.z, acc[r][2]);
      acc[r][3] = fmaf(xv, w.w, acc[r][3]);
    }
  }
  #pragma unroll
  for (int r = 0; r < 8; ++r) {
    int node = blockIdx.x * 64 + rg * 8 + r;
    float dv = dinv[node];
    float4 o = make_float4(acc[r][0] * dv, acc[r][1] * dv,
                           acc[r][2] * dv, acc[r][3] * dv);
    *(float4*)&g[(size_t)node * HID + cg * 4] = o;
  }
}

// ---- Aggregation 1 fused with bias+ReLU+GEMM2+scale --------------------
// One wave per node; lane l owns features 2l, 2l+1.
// g2[i] = dinv[i] * ( relu(dinv[i]*(g[i]+sum_in g[src]) + b1) @ W2 )

__global__ __launch_bounds__(256) void k_agg1(const float* __restrict__ g,
                                              const int* __restrict__ row_start,
                                              const int* __restrict__ row_end,
                                              const int* __restrict__ csr,
                                              const float* __restrict__ dinv,
                                              const float* __restrict__ b1,
                                              const float* __restrict__ W2,
                                              float* __restrict__ g2) {
  int node = blockIdx.x * 4 + (threadIdx.x >> 6);
  int lane = threadIdx.x & 63;

  float2 s = *(const float2*)&g[(size_t)node * HID + lane * 2];  // self loop
  int e0 = row_start[node];
  int e1 = row_end[node];
  for (int e = e0; e < e1; ++e) {
    int src = csr[e];
    float2 m = *(const float2*)&g[(size_t)src * HID + lane * 2];
    s.x += m.x;
    s.y += m.y;
  }
  float dv = dinv[node];
  float2 bb = *(const float2*)&b1[lane * 2];
  float hx = fmaxf(fmaf(s.x, dv, bb.x), 0.f);
  float hy = fmaxf(fmaf(s.y, dv, bb.y), 0.f);
  // W2 is [128][2] row-major; lane l needs rows 2l, 2l+1 -> float4 at 4l
  float4 w = *(const float4*)&W2[lane * 4];
  float p0 = hx * w.x + hy * w.z;
  float p1 = hx * w.y + hy * w.w;
  #pragma unroll
  for (int off = 32; off > 0; off >>= 1) {
    p0 += __shfl_xor(p0, off);
    p1 += __shfl_xor(p1, off);
  }
  if (lane == 0) {
    float2 o;
    o.x = p0 * dv;
    o.y = p1 * dv;
    *(float2*)&g2[(size_t)node * 2] = o;
  }
}

// ---- Aggregation 2 (width 2) -------------------------------------------
// out[i] = dinv[i] * (g2[i] + sum_in g2[src]) + b2

__global__ __launch_bounds__(256) void k_agg2(const float2* __restrict__ g2,
                                              const int* __restrict__ row_start,
                                              const int* __restrict__ row_end,
                                              const int* __restrict__ csr,
                                              const float* __restrict__ dinv,
                                              const float* __restrict__ b2,
                                              float* __restrict__ out) {
  int i = blockIdx.x * 256 + threadIdx.x;
  if (i >= N_NODES) return;
  float2 s = g2[i];
  int e1 = row_end[i];
  for (int e = row_start[i]; e < e1; ++e) {
    float2 m = g2[csr[e]];
    s.x += m.x;
    s.y += m.y;
  }
  float dv = dinv[i];
  float2 o;
  o.x = fmaf(s.x, dv, b2[0]);
  o.y = fmaf(s.y, dv, b2[1]);
  *(float2*)&out[(size_t)i * 2] = o;
}

// ---- launch -------------------------------------------------------------

extern "C" void kernel_launch(void* const* d_in, const int* in_sizes, int n_in,
                              void* d_out, int out_size, void* d_ws, size_t ws_size,
                              hipStream_t stream) {
  const float* x  = (const float*)d_in[0];
  const int*   ei = (const int*)d_in[1];
  const float* W1 = (const float*)d_in[2];
  const float* b1 = (const float*)d_in[3];
  const float* W2 = (const float*)d_in[4];
  const float* b2 = (const float*)d_in[5];
  float* out = (float*)d_out;

  char* ws = (char*)d_ws;
  size_t off = 0;
  auto take = [&](size_t bytes) -> char* {
    char* p = ws + off;
    off = (off + bytes + 255) & ~(size_t)255;
    return p;
  };
  int*   counts    = (int*)  take((size_t)N_NODES * 4);
  int*   row_start = (int*)  take((size_t)N_NODES * 4);
  int*   cursor    = (int*)  take((size_t)N_NODES * 4);
  int*   aux       = (int*)  take(512);
  float* dinv      = (float*)take((size_t)N_NODES * 4);
  int*   csr       = (int*)  take((size_t)N_EDGES * 4);
  float* g2        = (float*)take((size_t)N_NODES * 2 * 4);
  float* g         = (float*)take((size_t)N_NODES * HID * 4);
  (void)ws_size; (void)in_sizes; (void)n_in; (void)out_size;

  hipMemsetAsync(counts, 0, (size_t)N_NODES * 4, stream);
  k_count<<<(N_EDGES + 255) / 256, 256, 0, stream>>>(ei, counts);
  k_dinv<<<(N_NODES + 255) / 256, 256, 0, stream>>>(counts, dinv);
  k_gemm1<<<N_NODES / 64, 256, 0, stream>>>(x, W1, dinv, g);
  k_scan1<<<SCAN_BLOCKS, 256, 0, stream>>>(counts, row_start, aux);
  k_scan2<<<1, 128, 0, stream>>>(aux);
  k_scan3<<<(N_NODES + 255) / 256, 256, 0, stream>>>(row_start, aux, cursor);
  k_place<<<(N_EDGES + 255) / 256, 256, 0, stream>>>(ei, cursor, csr);
  k_agg1<<<N_NODES / 4, 256, 0, stream>>>(g, row_start, cursor, csr, dinv, b1, W2, g2);
  k_agg2<<<(N_NODES + 255) / 256, 256, 0, stream>>>((const float2*)g2, row_start, cursor,
                                                    csr, dinv, b2, out);
}

// Round 2
// 189.293 us; speedup vs baseline: 1.4437x; 1.4437x over previous
//
#include <hip/hip_runtime.h>
#include <hip/hip_bf16.h>

typedef __attribute__((ext_vector_type(8))) short bf16x8;
typedef __attribute__((ext_vector_type(4))) float f32x4;

#define N_NODES 200000
#define N_EDGES 400000
#define F_IN    165
#define HID     128
#define SCAN_CHUNK 2048
#define SCAN_BLOCKS 98   // ceil(200000/2048)

// gemm1 tiling
#define BM     64
#define KSTEPS 6         // 6*32 = 192 >= 165 (zero-padded)
#define K_LDS  200       // bf16 row pitch: 400B = 100 dwords -> +4 banks/row

// ---- CSR build ----------------------------------------------------------

__global__ __launch_bounds__(256) void k_count(const int* __restrict__ ei,
                                               int* __restrict__ counts) {
  int e = blockIdx.x * 256 + threadIdx.x;
  if (e < N_EDGES) atomicAdd(&counts[ei[N_EDGES + e]], 1);
}

__global__ __launch_bounds__(256) void k_dinv(const int* __restrict__ counts,
                                              float* __restrict__ dinv) {
  int i = blockIdx.x * 256 + threadIdx.x;
  if (i < N_NODES) dinv[i] = rsqrtf(1.0f + (float)counts[i]);
}

__global__ __launch_bounds__(256) void k_scan1(const int* __restrict__ counts,
                                               int* __restrict__ row_start,
                                               int* __restrict__ aux) {
  __shared__ int lds[256];
  int t = threadIdx.x;
  int base = blockIdx.x * SCAN_CHUNK + t * 8;
  int v[8], pre[8];
  int s = 0;
  #pragma unroll
  for (int j = 0; j < 8; ++j) {
    int i = base + j;
    v[j] = (i < N_NODES) ? counts[i] : 0;
    pre[j] = s;
    s += v[j];
  }
  lds[t] = s;
  __syncthreads();
  int incl = s;
  for (int off = 1; off < 256; off <<= 1) {
    int y = (t >= off) ? lds[t - off] : 0;
    __syncthreads();
    incl += y;
    lds[t] = incl;
    __syncthreads();
  }
  int excl = incl - s;
  #pragma unroll
  for (int j = 0; j < 8; ++j) {
    int i = base + j;
    if (i < N_NODES) row_start[i] = excl + pre[j];
  }
  if (t == 255) aux[blockIdx.x] = incl;
}

__global__ void k_scan2(int* __restrict__ aux) {  // 1 block, 128 threads
  __shared__ int lds[128];
  int t = threadIdx.x;
  int s = (t < SCAN_BLOCKS) ? aux[t] : 0;
  lds[t] = s;
  __syncthreads();
  int incl = s;
  for (int off = 1; off < 128; off <<= 1) {
    int y = (t >= off) ? lds[t - off] : 0;
    __syncthreads();
    incl += y;
    lds[t] = incl;
    __syncthreads();
  }
  if (t < SCAN_BLOCKS) aux[t] = incl - s;  // exclusive
}

__global__ __launch_bounds__(256) void k_scan3(int* __restrict__ row_start,
                                               const int* __restrict__ aux,
                                               int* __restrict__ cursor) {
  int i = blockIdx.x * 256 + threadIdx.x;
  if (i < N_NODES) {
    int r = row_start[i] + aux[i >> 11];
    row_start[i] = r;
    cursor[i] = r;
  }
}

__global__ __launch_bounds__(256) void k_place(const int* __restrict__ ei,
                                               int* __restrict__ cursor,
                                               int* __restrict__ csr) {
  int e = blockIdx.x * 256 + threadIdx.x;
  if (e < N_EDGES) {
    int d = ei[N_EDGES + e];
    int pos = atomicAdd(&cursor[d], 1);
    csr[pos] = ei[e];
  }
}

// ---- W1 -> bf16, pre-laid-out in MFMA B-fragment order ------------------
// Wf[((ct*6 + s)*64 + lane)*8 + j] = bf16(W1[k][col]),
//   k = s*32 + (lane>>4)*8 + j, col = ct*16 + (lane&15), 0 for k >= 165.

__global__ __launch_bounds__(256) void k_w1bf(const float* __restrict__ W1,
                                              ushort* __restrict__ Wf) {
  int id = blockIdx.x * 256 + threadIdx.x;   // < 8*6*64*8 = 24576
  int j = id & 7;
  int lane = (id >> 3) & 63;
  int rem = id >> 9;          // ct*6 + s, < 48
  int s = rem % 6;
  int ct = rem / 6;
  int k = s * 32 + (lane >> 4) * 8 + j;
  int col = ct * 16 + (lane & 15);
  float v = (k < F_IN) ? W1[k * HID + col] : 0.f;
  uint u = __builtin_bit_cast(uint, v);
  Wf[id] = (ushort)((u + 0x7FFF + ((u >> 16) & 1)) >> 16);
}

// ---- GEMM1 via MFMA: g = (x @ W1) * dinv[row]  --------------------------
// 64 rows/block, 4 waves; wave w owns col-tiles {2w, 2w+1} (all 64 rows).

__global__ __launch_bounds__(256) void k_gemm1(const float* __restrict__ x,
                                               const ushort* __restrict__ Wf,
                                               const float* __restrict__ dinv,
                                               float* __restrict__ g) {
  __shared__ ushort xs[BM][K_LDS];
  const int tid  = threadIdx.x;
  const int wave = tid >> 6;
  const int lane = tid & 63;
  const int r15  = lane & 15;
  const int kg   = lane >> 4;

  // B fragments (issued first; overlap with staging)
  bf16x8 bfrag[2][KSTEPS];
  #pragma unroll
  for (int t = 0; t < 2; ++t) {
    int ct = wave * 2 + t;
    #pragma unroll
    for (int s = 0; s < KSTEPS; ++s)
      bfrag[t][s] = *(const bf16x8*)(Wf + (((ct * KSTEPS + s) * 64 + lane) << 3));
  }

  // zero LDS (covers the K=165..192 pad), then stage x tile as bf16
  uint4 z4 = make_uint4(0, 0, 0, 0);
  for (int i = tid; i < (BM * K_LDS * 2 / 16); i += 256) ((uint4*)xs)[i] = z4;
  __syncthreads();
  const float4* xg = (const float4*)(x + (size_t)blockIdx.x * (BM * F_IN));
  for (int i = tid; i < (BM * F_IN / 4); i += 256) {
    float4 v = xg[i];
    int f = i * 4;
    float vv[4] = {v.x, v.y, v.z, v.w};
    #pragma unroll
    for (int e = 0; e < 4; ++e) {
      int ff = f + e;
      int row = (int)__umulhi((uint)ff, 26030106u);  // ff / 165, exact for ff < 2^22
      int k = ff - row * 165;
      uint u = __builtin_bit_cast(uint, vv[e]);
      xs[row][k] = (ushort)((u + 0x7FFF + ((u >> 16) & 1)) >> 16);
    }
  }
  __syncthreads();

  f32x4 acc[4][2];
  #pragma unroll
  for (int rg = 0; rg < 4; ++rg)
    #pragma unroll
    for (int t = 0; t < 2; ++t)
      acc[rg][t] = (f32x4){0.f, 0.f, 0.f, 0.f};

  #pragma unroll
  for (int rg = 0; rg < 4; ++rg) {
    #pragma unroll
    for (int s = 0; s < KSTEPS; ++s) {
      bf16x8 a = *(const bf16x8*)&xs[rg * 16 + r15][s * 32 + kg * 8];
      acc[rg][0] = __builtin_amdgcn_mfma_f32_16x16x32_bf16(a, bfrag[0][s], acc[rg][0], 0, 0, 0);
      acc[rg][1] = __builtin_amdgcn_mfma_f32_16x16x32_bf16(a, bfrag[1][s], acc[rg][1], 0, 0, 0);
    }
  }

  // epilogue: scale by dinv[row], store fp32
  int base = blockIdx.x * BM;
  #pragma unroll
  for (int rg = 0; rg < 4; ++rg) {
    #pragma unroll
    for (int r = 0; r < 4; ++r) {
      int row = base + rg * 16 + kg * 4 + r;
      float dv = dinv[row];
      #pragma unroll
      for (int t = 0; t < 2; ++t) {
        int col = (wave * 2 + t) * 16 + r15;
        g[(size_t)row * HID + col] = acc[rg][t][r] * dv;
      }
    }
  }
}

// ---- Aggregation 1 fused with bias+ReLU+GEMM2+scale --------------------
// One wave per node; lane l owns features 2l, 2l+1.
// g2[i] = dinv[i] * ( relu(dinv[i]*(g[i]+sum_in g[src]) + b1) @ W2 )

__global__ __launch_bounds__(256) void k_agg1(const float* __restrict__ g,
                                              const int* __restrict__ row_start,
                                              const int* __restrict__ row_end,
                                              const int* __restrict__ csr,
                                              const float* __restrict__ dinv,
                                              const float* __restrict__ b1,
                                              const float* __restrict__ W2,
                                              float* __restrict__ g2) {
  int node = blockIdx.x * 4 + (threadIdx.x >> 6);
  int lane = threadIdx.x & 63;

  float2 s = *(const float2*)&g[(size_t)node * HID + lane * 2];  // self loop
  int e0 = row_start[node];
  int e1 = row_end[node];
  for (int e = e0; e < e1; ++e) {
    int src = csr[e];
    float2 m = *(const float2*)&g[(size_t)src * HID + lane * 2];
    s.x += m.x;
    s.y += m.y;
  }
  float dv = dinv[node];
  float2 bb = *(const float2*)&b1[lane * 2];
  float hx = fmaxf(fmaf(s.x, dv, bb.x), 0.f);
  float hy = fmaxf(fmaf(s.y, dv, bb.y), 0.f);
  float4 w = *(const float4*)&W2[lane * 4];
  float p0 = hx * w.x + hy * w.z;
  float p1 = hx * w.y + hy * w.w;
  #pragma unroll
  for (int off = 32; off > 0; off >>= 1) {
    p0 += __shfl_xor(p0, off);
    p1 += __shfl_xor(p1, off);
  }
  if (lane == 0) {
    float2 o;
    o.x = p0 * dv;
    o.y = p1 * dv;
    *(float2*)&g2[(size_t)node * 2] = o;
  }
}

// ---- Aggregation 2 (width 2) -------------------------------------------

__global__ __launch_bounds__(256) void k_agg2(const float2* __restrict__ g2,
                                              const int* __restrict__ row_start,
                                              const int* __restrict__ row_end,
                                              const int* __restrict__ csr,
                                              const float* __restrict__ dinv,
                                              const float* __restrict__ b2,
                                              float* __restrict__ out) {
  int i = blockIdx.x * 256 + threadIdx.x;
  if (i >= N_NODES) return;
  float2 s = g2[i];
  int e1 = row_end[i];
  for (int e = row_start[i]; e < e1; ++e) {
    float2 m = g2[csr[e]];
    s.x += m.x;
    s.y += m.y;
  }
  float dv = dinv[i];
  float2 o;
  o.x = fmaf(s.x, dv, b2[0]);
  o.y = fmaf(s.y, dv, b2[1]);
  *(float2*)&out[(size_t)i * 2] = o;
}

// ---- launch -------------------------------------------------------------

extern "C" void kernel_launch(void* const* d_in, const int* in_sizes, int n_in,
                              void* d_out, int out_size, void* d_ws, size_t ws_size,
                              hipStream_t stream) {
  const float* x  = (const float*)d_in[0];
  const int*   ei = (const int*)d_in[1];
  const float* W1 = (const float*)d_in[2];
  const float* b1 = (const float*)d_in[3];
  const float* W2 = (const float*)d_in[4];
  const float* b2 = (const float*)d_in[5];
  float* out = (float*)d_out;

  char* ws = (char*)d_ws;
  size_t off = 0;
  auto take = [&](size_t bytes) -> char* {
    char* p = ws + off;
    off = (off + bytes + 255) & ~(size_t)255;
    return p;
  };
  int*    counts    = (int*)   take((size_t)N_NODES * 4);
  int*    row_start = (int*)   take((size_t)N_NODES * 4);
  int*    cursor    = (int*)   take((size_t)N_NODES * 4);
  int*    aux       = (int*)   take(512);
  float*  dinv      = (float*) take((size_t)N_NODES * 4);
  int*    csr       = (int*)   take((size_t)N_EDGES * 4);
  float*  g2        = (float*) take((size_t)N_NODES * 2 * 4);
  ushort* Wf        = (ushort*)take((size_t)8 * KSTEPS * 64 * 8 * 2);
  float*  g         = (float*) take((size_t)N_NODES * HID * 4);
  (void)ws_size; (void)in_sizes; (void)n_in; (void)out_size;

  hipMemsetAsync(counts, 0, (size_t)N_NODES * 4, stream);
  k_count<<<(N_EDGES + 255) / 256, 256, 0, stream>>>(ei, counts);
  k_dinv<<<(N_NODES + 255) / 256, 256, 0, stream>>>(counts, dinv);
  k_w1bf<<<96, 256, 0, stream>>>(W1, Wf);
  k_gemm1<<<N_NODES / BM, 256, 0, stream>>>(x, Wf, dinv, g);
  k_scan1<<<SCAN_BLOCKS, 256, 0, stream>>>(counts, row_start, aux);
  k_scan2<<<1, 128, 0, stream>>>(aux);
  k_scan3<<<(N_NODES + 255) / 256, 256, 0, stream>>>(row_start, aux, cursor);
  k_place<<<(N_EDGES + 255) / 256, 256, 0, stream>>>(ei, cursor, csr);
  k_agg1<<<N_NODES / 4, 256, 0, stream>>>(g, row_start, cursor, csr, dinv, b1, W2, g2);
  k_agg2<<<(N_NODES + 255) / 256, 256, 0, stream>>>((const float2*)g2, row_start, cursor,
                                                    csr, dinv, b2, out);
}